// Round 13
// baseline (230.817 us; speedup 1.0000x reference)
//
#include <hip/hip_runtime.h>
#include <hip/hip_bf16.h>

// FastBinaryLinear: y[t,o] = scale[o] * sum_i x[t,i]*sign(w[o,i])
// R13: i8 path with mfma_i32_32x32x32_i8. 128x256 tile, BK=64, 8 waves
// (wave-tile 64x64 = 2x2 32x32 MFMA tiles, acc=64 VGPR -> ~100 total ->
// 4 waves/SIMD, 2 blocks/CU). Triple-buffered LDS (3x24KB), r10-verified
// gate discipline (VMC before BAR; reads after BAR).
// LDS layout (re-derived for 32-row frags): row r, 4x16B granules; slot s
// holds global granule s^(r&3); reader lane (r31=l&31, hi=l>>5) reads slot
// ((kk<<1)^hi)^(r31&3) -> granule (kk<<1)|hi. Bank-balanced (8 lanes/group).

typedef int i32x4 __attribute__((ext_vector_type(4)));
typedef int i32x16 __attribute__((ext_vector_type(16)));
typedef const __attribute__((address_space(1))) void* gptr_t;
typedef __attribute__((address_space(3))) void* lptr_t;

template<bool V> struct BoolC { static constexpr bool value = V; };

// ---- fused pre-pass: blocks [0,M) quantize x rows; [M, M+N) sign w rows ----
__global__ __launch_bounds__(256) void prep_kernel(
    const float4* __restrict__ x, const float4* __restrict__ w,
    unsigned* __restrict__ xq, unsigned* __restrict__ wq,
    float* __restrict__ alpha, int M, int N, int K) {
  const int bid = blockIdx.x;
  const int t = threadIdx.x;
  const int n4 = K >> 2;

  if (bid < M) {
    const int row = bid;
    const float4* xr = x + (size_t)row * n4;
    unsigned* qr = xq + (size_t)row * n4;

    float m = 0.f;
    for (int i = t; i < n4; i += 256) {
      float4 v = xr[i];
      m = fmaxf(m, fmaxf(fmaxf(fabsf(v.x), fabsf(v.y)), fmaxf(fabsf(v.z), fabsf(v.w))));
    }
    for (int o = 32; o > 0; o >>= 1) m = fmaxf(m, __shfl_xor(m, o));
    __shared__ float wm_[4];
    if ((t & 63) == 0) wm_[t >> 6] = m;
    __syncthreads();
    m = fmaxf(fmaxf(wm_[0], wm_[1]), fmaxf(wm_[2], wm_[3]));

    const float inv = m > 0.f ? 127.f / m : 0.f;
    if (t == 0) alpha[row] = m > 0.f ? m / 127.f : 0.f;

    for (int i = t; i < n4; i += 256) {
      float4 v = xr[i];  // cache-resident re-read
      int q0 = (int)rintf(v.x * inv), q1 = (int)rintf(v.y * inv);
      int q2 = (int)rintf(v.z * inv), q3 = (int)rintf(v.w * inv);
      qr[i] = (unsigned)(q0 & 255) | ((unsigned)(q1 & 255) << 8) |
              ((unsigned)(q2 & 255) << 16) | ((unsigned)(q3 & 255) << 24);
    }
  } else {
    const int row = bid - M;
    const float4* wr = w + (size_t)row * n4;
    unsigned* qr = wq + (size_t)row * n4;
    for (int i = t; i < n4; i += 256) {
      float4 f = wr[i];
      int s0 = (f.x > 0.f) - (f.x < 0.f);
      int s1 = (f.y > 0.f) - (f.y < 0.f);
      int s2 = (f.z > 0.f) - (f.z < 0.f);
      int s3 = (f.w > 0.f) - (f.w < 0.f);
      qr[i] = (unsigned)(s0 & 255) | ((unsigned)(s1 & 255) << 8) |
              ((unsigned)(s2 & 255) << 16) | ((unsigned)(s3 & 255) << 24);
    }
  }
}

// ---- 128x256 BK=64 i8 GEMM (32x32x32 MFMA), triple-buffered ----
// Buffer (24KB): A 128r x 64B @0, B 256r x 64B @8192.
__global__ __launch_bounds__(512, 4) void gemm32_i8_kernel(
    const signed char* __restrict__ A,   // [M][K] i8 (quantized x)
    const signed char* __restrict__ B,   // [N][K] i8 (sign w)
    const float* __restrict__ scale,     // [N]
    const float* __restrict__ alpha,     // [M]
    float* __restrict__ C,               // [M][N] f32
    int M, int N, int K) {
  __shared__ __align__(16) char lds[73728];   // 3 x 24576

  const int t = threadIdx.x;
  const int lane = t & 63;
  const int wv = t >> 6;
  const int wm = wv >> 2;   // 0..1: 64-row half of BM=128
  const int wn = wv & 3;    // 0..3: 64-col quarter of BN=256

  const int nbn = N >> 8;
  const int bn = blockIdx.x % nbn;
  const int bm = blockIdx.x / nbn;
  const int m0 = bm << 7, n0 = bn << 8;

  // staging: 8KB issue = 128 rows x 64B; thread t -> row t>>2, slot t&3,
  // fetching global granule (t&3) ^ ((t>>2)&3).
  const int rlo = t >> 2;
  const int gsw = (t & 3) ^ ((t >> 2) & 3);
  const signed char* gA = A + (size_t)(m0 + rlo) * K + gsw * 16;
  const signed char* gB = B + (size_t)(n0 + rlo) * K + gsw * 16;
  const int stBase = wv << 10;  // wave-uniform; HW adds lane*16

  // read lane coords
  const int r31 = lane & 31;
  const int hi = lane >> 5;
  const int k3 = r31 & 3;
  // slot(kk) = ((kk<<1) ^ hi ^ k3); addr = row*64 + slot*16
  const int aRowB = (wm * 64 + r31) * 64;          // + m*2048
  const int bRowB = 8192 + (wn * 64 + r31) * 64;   // + n*2048
  const int sl0 = (hi ^ k3) << 4;                  // kk=0 slot byte
  const int sl1 = ((2 ^ hi ^ k3) & 3) << 4;        // kk=1 slot byte

#define BUFO(J) ((((J) % 3)) * 24576)
#define STAGE_T(KT)                                                           \
  do {                                                                        \
    const int o_ = BUFO(KT);                                                  \
    __builtin_amdgcn_global_load_lds((gptr_t)(gA + (size_t)(KT)*64),          \
        (lptr_t)(lds + o_ + stBase), 16, 0, 0);                               \
    __builtin_amdgcn_global_load_lds((gptr_t)(gB + (size_t)(KT)*64),          \
        (lptr_t)(lds + o_ + 8192 + stBase), 16, 0, 0);                        \
    __builtin_amdgcn_global_load_lds(                                         \
        (gptr_t)(gB + (size_t)128 * K + (size_t)(KT)*64),                     \
        (lptr_t)(lds + o_ + 16384 + stBase), 16, 0, 0);                       \
  } while (0)

#define BAR() asm volatile("s_barrier" ::: "memory")
#define VMC(NN) asm volatile("s_waitcnt vmcnt(" #NN ")" ::: "memory")

#define RD4(OFF) (*(const i32x4*)(lds + (OFF)))
#define READ_KK(SLB, BUF)                                             \
  do {                                                                \
    aq[0] = RD4((BUF) + aRowB + (SLB));                               \
    aq[1] = RD4((BUF) + aRowB + 2048 + (SLB));                        \
    bq[0] = RD4((BUF) + bRowB + (SLB));                               \
    bq[1] = RD4((BUF) + bRowB + 2048 + (SLB));                        \
  } while (0)

#define MFMA4()                                                       \
  do {                                                                \
    __builtin_amdgcn_s_setprio(1);                                    \
    acc[0][0] = __builtin_amdgcn_mfma_i32_32x32x32_i8(aq[0], bq[0], acc[0][0], 0, 0, 0); \
    acc[0][1] = __builtin_amdgcn_mfma_i32_32x32x32_i8(aq[0], bq[1], acc[0][1], 0, 0, 0); \
    acc[1][0] = __builtin_amdgcn_mfma_i32_32x32x32_i8(aq[1], bq[0], acc[1][0], 0, 0, 0); \
    acc[1][1] = __builtin_amdgcn_mfma_i32_32x32x32_i8(aq[1], bq[1], acc[1][1], 0, 0, 0); \
    __builtin_amdgcn_s_setprio(0);                                    \
  } while (0)

  i32x16 acc[2][2];
#pragma unroll
  for (int i = 0; i < 2; i++)
#pragma unroll
    for (int j = 0; j < 2; j++) acc[i][j] = (i32x16)(0);

  i32x4 aq[2], bq[2];

  // ---- prologue: T0->buf0, T1->buf1; VMC(3) -> T0 landed ----
  STAGE_T(0);
  STAGE_T(1);
  VMC(3);
  BAR();

  // Tile j (buf j%3): stage T(j+2) into buf (j+2)%3 (= buf of T(j-1),
  // whose reads completed before tile j-1's MFMAs, >=2 barriers ago).
  // Gate at phase end before BAR: VMC(3) -> T(j+1) complete.
  auto tile = [&](int kt, int rd, auto stagec, auto gzc) {
    constexpr bool STG = decltype(stagec)::value;
    constexpr bool GZ = decltype(gzc)::value;
    // ===== phase A: kk=0 =====
    READ_KK(sl0, rd);
    BAR();
    MFMA4();
    BAR();
    // ===== phase B: kk=1, stage, gate =====
    READ_KK(sl1, rd);
    if constexpr (STG) { STAGE_T(kt + 2); }
    BAR();
    MFMA4();
    if constexpr (STG) { VMC(3); }
    else if constexpr (GZ) { VMC(0); }
    BAR();
  };

  const int nt = K >> 6;   // >= 8 by guard
  for (int j = 0; j < nt - 2; ++j) tile(j, BUFO(j), BoolC<true>{}, BoolC<false>{});
  tile(nt - 2, BUFO(nt - 2), BoolC<false>{}, BoolC<true>{});
  tile(nt - 1, BUFO(nt - 1), BoolC<false>{}, BoolC<false>{});

  // ---- epilogue: 32x32 C/D: col=lane&31, row=(j&3)+8*(j>>2)+4*hi ----
#pragma unroll
  for (int n = 0; n < 2; n++) {
    const int col = n0 + wn * 64 + n * 32 + r31;
    const float s = scale[col];
#pragma unroll
    for (int m = 0; m < 2; m++) {
      const int rbase = m0 + wm * 64 + m * 32 + 4 * hi;
#pragma unroll
      for (int j = 0; j < 16; j++) {
        const int row = rbase + (j & 3) + 8 * (j >> 2);
        C[(size_t)row * N + col] = (float)acc[m][n][j] * (s * alpha[row]);
      }
    }
  }
#undef BUFO
#undef STAGE_T
#undef BAR
#undef VMC
#undef RD4
#undef READ_KK
#undef MFMA4
}

// ---- fallback: f32 tiled GEMM (odd shapes / tiny ws) ----
__global__ __launch_bounds__(256) void fallback_gemm_kernel(
    const float* __restrict__ x, const float* __restrict__ w,
    const float* __restrict__ scale, float* __restrict__ out,
    int M, int N, int K) {
  __shared__ float xs[16][17];
  __shared__ float ws_[16][17];
  int nb = N / 16;
  int bx = blockIdx.x % nb;
  int by = blockIdx.x / nb;
  int tx = threadIdx.x % 16;
  int ty = threadIdx.x / 16;
  float acc = 0.f;
  for (int k0 = 0; k0 < K; k0 += 16) {
    xs[ty][tx] = x[(size_t)(by * 16 + ty) * K + k0 + tx];
    float wv = w[(size_t)(bx * 16 + ty) * K + k0 + tx];
    ws_[ty][tx] = (float)((wv > 0.f) - (wv < 0.f));
    __syncthreads();
#pragma unroll
    for (int kk = 0; kk < 16; kk++) acc += xs[ty][kk] * ws_[tx][kk];
    __syncthreads();
  }
  int row = by * 16 + ty, col = bx * 16 + tx;
  out[(size_t)row * N + col] = acc * scale[col];
}

extern "C" void kernel_launch(void* const* d_in, const int* in_sizes, int n_in,
                              void* d_out, int out_size, void* d_ws, size_t ws_size,
                              hipStream_t stream) {
  const float* x = (const float*)d_in[0];
  const float* w = (const float*)d_in[1];
  const float* scale = (const float*)d_in[2];
  float* out = (float*)d_out;

  const int N = in_sizes[2];
  const int K = in_sizes[1] / N;
  const int M = in_sizes[0] / K;

  const size_t xq_bytes = (size_t)M * K;
  const size_t wq_bytes = (size_t)N * K;
  const size_t al_bytes = (size_t)M * 4;
  const bool shapes_ok = (M % 128 == 0) && (N % 256 == 0) && (K % 128 == 0) && (K >= 512);

  if (shapes_ok && ws_size >= xq_bytes + wq_bytes + al_bytes) {
    signed char* xq = (signed char*)d_ws;
    signed char* wq = (signed char*)((char*)d_ws + xq_bytes);
    float* alpha = (float*)((char*)d_ws + xq_bytes + wq_bytes);

    prep_kernel<<<M + N, 256, 0, stream>>>((const float4*)x, (const float4*)w,
                                           (unsigned*)xq, (unsigned*)wq, alpha, M, N, K);

    int grid = (M / 128) * (N / 256);
    gemm32_i8_kernel<<<grid, 512, 0, stream>>>(xq, wq, scale, alpha, out, M, N, K);
  } else {
    int grid = (M / 16) * (N / 16);
    fallback_gemm_kernel<<<grid, 256, 0, stream>>>(x, w, scale, out, M, N, K);
  }
}

// Round 14
// 191.059 us; speedup vs baseline: 1.2081x; 1.2081x over previous
//
#include <hip/hip_runtime.h>
#include <hip/hip_bf16.h>

// FastBinaryLinear: y[t,o] = scale[o] * sum_i x[t,i]*sign(w[o,i])
// R14: i8 path, 256x256 tile, BK=64, 8 waves (wave-tile 128x64, 16x16x64
// MFMA, acc 128 VGPR). COARSE groups: ONE barrier per 2 K-tiles; 4 LDS
// buffers x 32KB; within-group no sync -> waves drift into LDS/MFMA
// anti-phase. Swizzle = r10-verified (key (r>>1)&3, 0 conflicts).

typedef int i32x4 __attribute__((ext_vector_type(4)));
typedef const __attribute__((address_space(1))) void* gptr_t;
typedef __attribute__((address_space(3))) void* lptr_t;

// ---- fused pre-pass: blocks [0,M) quantize x rows; [M, M+N) sign w rows ----
__global__ __launch_bounds__(256) void prep_kernel(
    const float4* __restrict__ x, const float4* __restrict__ w,
    unsigned* __restrict__ xq, unsigned* __restrict__ wq,
    float* __restrict__ alpha, int M, int N, int K) {
  const int bid = blockIdx.x;
  const int t = threadIdx.x;
  const int n4 = K >> 2;

  if (bid < M) {
    const int row = bid;
    const float4* xr = x + (size_t)row * n4;
    unsigned* qr = xq + (size_t)row * n4;

    float m = 0.f;
    for (int i = t; i < n4; i += 256) {
      float4 v = xr[i];
      m = fmaxf(m, fmaxf(fmaxf(fabsf(v.x), fabsf(v.y)), fmaxf(fabsf(v.z), fabsf(v.w))));
    }
    for (int o = 32; o > 0; o >>= 1) m = fmaxf(m, __shfl_xor(m, o));
    __shared__ float wm_[4];
    if ((t & 63) == 0) wm_[t >> 6] = m;
    __syncthreads();
    m = fmaxf(fmaxf(wm_[0], wm_[1]), fmaxf(wm_[2], wm_[3]));

    const float inv = m > 0.f ? 127.f / m : 0.f;
    if (t == 0) alpha[row] = m > 0.f ? m / 127.f : 0.f;

    for (int i = t; i < n4; i += 256) {
      float4 v = xr[i];  // cache-resident re-read
      int q0 = (int)rintf(v.x * inv), q1 = (int)rintf(v.y * inv);
      int q2 = (int)rintf(v.z * inv), q3 = (int)rintf(v.w * inv);
      qr[i] = (unsigned)(q0 & 255) | ((unsigned)(q1 & 255) << 8) |
              ((unsigned)(q2 & 255) << 16) | ((unsigned)(q3 & 255) << 24);
    }
  } else {
    const int row = bid - M;
    const float4* wr = w + (size_t)row * n4;
    unsigned* qr = wq + (size_t)row * n4;
    for (int i = t; i < n4; i += 256) {
      float4 f = wr[i];
      int s0 = (f.x > 0.f) - (f.x < 0.f);
      int s1 = (f.y > 0.f) - (f.y < 0.f);
      int s2 = (f.z > 0.f) - (f.z < 0.f);
      int s3 = (f.w > 0.f) - (f.w < 0.f);
      qr[i] = (unsigned)(s0 & 255) | ((unsigned)(s1 & 255) << 8) |
              ((unsigned)(s2 & 255) << 16) | ((unsigned)(s3 & 255) << 24);
    }
  }
}

// ---- 256x256 BK=64 i8 GEMM, 4-buffer coarse-group schedule ----
// Buffer (32KB): A 256r x 64B @0, B 256r x 64B @16384. Subtile 16r x 64B;
// stored slot s holds global granule s^((r>>1)&3); staging thread t (row
// t>>2, slot t&3) fetches granule (t&3)^((t>>3)&3); reader lane (rho,G)
// reads slot G^((rho>>1)&3).  [r10-verified: 0 conflicts]
__global__ __launch_bounds__(512, 2) void gemm256g_i8_kernel(
    const signed char* __restrict__ A,   // [M][K] i8 (quantized x)
    const signed char* __restrict__ B,   // [N][K] i8 (sign w)
    const float* __restrict__ scale,     // [N]
    const float* __restrict__ alpha,     // [M]
    float* __restrict__ C,               // [M][N] f32
    int M, int N, int K) {
  __shared__ __align__(16) char lds[131072];   // 4 x 32768

  const int t = threadIdx.x;
  const int lane = t & 63;
  const int wv = t >> 6;
  const int wm = wv >> 2;   // 0..1: 128-row half of BM=256
  const int wn = wv & 3;    // 0..3: 64-col quarter of BN=256

  const int nbn = N >> 8;
  const int bn = blockIdx.x % nbn;
  const int bm = blockIdx.x / nbn;
  const int m0 = bm << 8, n0 = bn << 8;

  // staging: 8KB issue = 128 rows x 64B; thread t -> row t>>2, slot t&3
  const int rlo = t >> 2;
  const int gsw = (t & 3) ^ ((t >> 3) & 3);
  const signed char* gA = A + (size_t)(m0 + rlo) * K + gsw * 16;
  const signed char* gB = B + (size_t)(n0 + rlo) * K + gsw * 16;
  const int stBase = wv << 10;  // wave-uniform; HW adds lane*16

  // ds_read lane bases
  const int rho = lane & 15;
  const int gix = (lane >> 4) ^ ((rho >> 1) & 3);
  const int dsA = (wm << 13) + (rho << 6) + (gix << 4);           // + mf*1024
  const int dsB = 16384 + (wn << 12) + (rho << 6) + (gix << 4);   // + nf*1024

#define BUFO(J) (((J) & 3) << 15)
#define STAGE_T(KT)                                                           \
  do {                                                                        \
    const int o_ = BUFO(KT);                                                  \
    __builtin_amdgcn_global_load_lds((gptr_t)(gA + (size_t)(KT)*64),          \
        (lptr_t)(lds + o_ + stBase), 16, 0, 0);                               \
    __builtin_amdgcn_global_load_lds(                                         \
        (gptr_t)(gA + (size_t)128 * K + (size_t)(KT)*64),                     \
        (lptr_t)(lds + o_ + 8192 + stBase), 16, 0, 0);                        \
    __builtin_amdgcn_global_load_lds((gptr_t)(gB + (size_t)(KT)*64),          \
        (lptr_t)(lds + o_ + 16384 + stBase), 16, 0, 0);                       \
    __builtin_amdgcn_global_load_lds(                                         \
        (gptr_t)(gB + (size_t)128 * K + (size_t)(KT)*64),                     \
        (lptr_t)(lds + o_ + 24576 + stBase), 16, 0, 0);                       \
  } while (0)

#define BAR() asm volatile("s_barrier" ::: "memory")
#define VMC0() asm volatile("s_waitcnt vmcnt(0)" ::: "memory")
#define LGKM0() asm volatile("s_waitcnt lgkmcnt(0)" ::: "memory")

  // per-tile compute: 4 B-frags then 4 mf-pair rounds (A2 + 8 MFMA)
#define TILE_COMPUTE(J)                                               \
  do {                                                                \
    const char* bp_ = lds + BUFO(J);                                  \
    i32x4 bq0 = *(const i32x4*)(bp_ + dsB);                           \
    i32x4 bq1 = *(const i32x4*)(bp_ + dsB + 1024);                    \
    i32x4 bq2 = *(const i32x4*)(bp_ + dsB + 2048);                    \
    i32x4 bq3 = *(const i32x4*)(bp_ + dsB + 3072);                    \
    _Pragma("unroll")                                                 \
    for (int mp = 0; mp < 4; mp++) {                                  \
      i32x4 a0 = *(const i32x4*)(bp_ + dsA + (2 * mp) * 1024);        \
      i32x4 a1 = *(const i32x4*)(bp_ + dsA + (2 * mp + 1) * 1024);    \
      __builtin_amdgcn_s_setprio(1);                                  \
      acc[2*mp][0]   = __builtin_amdgcn_mfma_i32_16x16x64_i8(a0, bq0, acc[2*mp][0], 0, 0, 0);   \
      acc[2*mp][1]   = __builtin_amdgcn_mfma_i32_16x16x64_i8(a0, bq1, acc[2*mp][1], 0, 0, 0);   \
      acc[2*mp][2]   = __builtin_amdgcn_mfma_i32_16x16x64_i8(a0, bq2, acc[2*mp][2], 0, 0, 0);   \
      acc[2*mp][3]   = __builtin_amdgcn_mfma_i32_16x16x64_i8(a0, bq3, acc[2*mp][3], 0, 0, 0);   \
      acc[2*mp+1][0] = __builtin_amdgcn_mfma_i32_16x16x64_i8(a1, bq0, acc[2*mp+1][0], 0, 0, 0); \
      acc[2*mp+1][1] = __builtin_amdgcn_mfma_i32_16x16x64_i8(a1, bq1, acc[2*mp+1][1], 0, 0, 0); \
      acc[2*mp+1][2] = __builtin_amdgcn_mfma_i32_16x16x64_i8(a1, bq2, acc[2*mp+1][2], 0, 0, 0); \
      acc[2*mp+1][3] = __builtin_amdgcn_mfma_i32_16x16x64_i8(a1, bq3, acc[2*mp+1][3], 0, 0, 0); \
      __builtin_amdgcn_s_setprio(0);                                  \
    }                                                                 \
  } while (0)

  i32x4 acc[8][4];
#pragma unroll
  for (int i = 0; i < 8; i++)
#pragma unroll
    for (int j = 0; j < 4; j++) acc[i][j] = (i32x4)(0);

  const int ng = K >> 7;   // groups of 2 K64-tiles (>= 2 by guard)

  // ---- prologue: stage T0,T1; full drain; barrier ----
  STAGE_T(0);
  STAGE_T(1);
  VMC0();
  BAR();

  // Group g: stage {T2g+2} ; compute T2g ; stage {T2g+3} ; compute T2g+1 ;
  // VMC0+LGKM0 ; BAR.  Writes bufs {2g+2,2g+3}&3, reads {2g,2g+1}&3 --
  // disjoint; WAR vs g-1 reads drained at g's opening barrier.
  for (int g = 0; g < ng; ++g) {
    const int j0 = 2 * g;
    const bool more = (g + 1 < ng);
    if (more) STAGE_T(j0 + 2);
    TILE_COMPUTE(j0);
    if (more) STAGE_T(j0 + 3);
    TILE_COMPUTE(j0 + 1);
    if (more) {
      VMC0();
      LGKM0();
      BAR();
    }
  }

  // ---- epilogue: C/D col=lane&15, row=(lane>>4)*4+j; y = acc*alpha*scale ----
  const int cc = lane & 15;
  const int cr4 = (lane >> 4) << 2;
#pragma unroll
  for (int nf = 0; nf < 4; nf++) {
    const int col = n0 + wn * 64 + nf * 16 + cc;
    const float s = scale[col];
#pragma unroll
    for (int mf = 0; mf < 8; mf++) {
      const int row = m0 + wm * 128 + mf * 16 + cr4;
#pragma unroll
      for (int jj = 0; jj < 4; jj++)
        C[(size_t)(row + jj) * N + col] = (float)acc[mf][nf][jj] * (s * alpha[row + jj]);
    }
  }
#undef BUFO
#undef STAGE_T
#undef BAR
#undef VMC0
#undef LGKM0
#undef TILE_COMPUTE
}

// ---- fallback: f32 tiled GEMM (odd shapes / tiny ws) ----
__global__ __launch_bounds__(256) void fallback_gemm_kernel(
    const float* __restrict__ x, const float* __restrict__ w,
    const float* __restrict__ scale, float* __restrict__ out,
    int M, int N, int K) {
  __shared__ float xs[16][17];
  __shared__ float ws_[16][17];
  int nb = N / 16;
  int bx = blockIdx.x % nb;
  int by = blockIdx.x / nb;
  int tx = threadIdx.x % 16;
  int ty = threadIdx.x / 16;
  float acc = 0.f;
  for (int k0 = 0; k0 < K; k0 += 16) {
    xs[ty][tx] = x[(size_t)(by * 16 + ty) * K + k0 + tx];
    float wv = w[(size_t)(bx * 16 + ty) * K + k0 + tx];
    ws_[ty][tx] = (float)((wv > 0.f) - (wv < 0.f));
    __syncthreads();
#pragma unroll
    for (int kk = 0; kk < 16; kk++) acc += xs[ty][kk] * ws_[tx][kk];
    __syncthreads();
  }
  int row = by * 16 + ty, col = bx * 16 + tx;
  out[(size_t)row * N + col] = acc * scale[col];
}

extern "C" void kernel_launch(void* const* d_in, const int* in_sizes, int n_in,
                              void* d_out, int out_size, void* d_ws, size_t ws_size,
                              hipStream_t stream) {
  const float* x = (const float*)d_in[0];
  const float* w = (const float*)d_in[1];
  const float* scale = (const float*)d_in[2];
  float* out = (float*)d_out;

  const int N = in_sizes[2];
  const int K = in_sizes[1] / N;
  const int M = in_sizes[0] / K;

  const size_t xq_bytes = (size_t)M * K;
  const size_t wq_bytes = (size_t)N * K;
  const size_t al_bytes = (size_t)M * 4;
  const bool shapes_ok = (M % 256 == 0) && (N % 256 == 0) && (K % 128 == 0) && (K >= 256);

  if (shapes_ok && ws_size >= xq_bytes + wq_bytes + al_bytes) {
    signed char* xq = (signed char*)d_ws;
    signed char* wq = (signed char*)((char*)d_ws + xq_bytes);
    float* alpha = (float*)((char*)d_ws + xq_bytes + wq_bytes);

    prep_kernel<<<M + N, 256, 0, stream>>>((const float4*)x, (const float4*)w,
                                           (unsigned*)xq, (unsigned*)wq, alpha, M, N, K);

    int grid = (M / 256) * (N / 256);
    gemm256g_i8_kernel<<<grid, 512, 0, stream>>>(xq, wq, scale, alpha, out, M, N, K);
  } else {
    int grid = (M / 16) * (N / 16);
    fallback_gemm_kernel<<<grid, 256, 0, stream>>>(x, w, scale, out, M, N, K);
  }
}